// Round 2
// baseline (411.474 us; speedup 1.0000x reference)
//
#include <hip/hip_runtime.h>
#include <hip/hip_bf16.h>

typedef __attribute__((ext_vector_type(8))) short short8;
typedef __attribute__((ext_vector_type(4))) float f32x4;
typedef __hip_bfloat16 bf16_t;

#define SEQ 2048
#define DM 1024
#define NH 16
#define DK 64

static __device__ __forceinline__ f32x4 mfma16x16x32(short8 a, short8 b, f32x4 c) {
  return __builtin_amdgcn_mfma_f32_16x16x32_bf16(a, b, c, 0, 0, 0);
}

// ---------------- dtype sniffer: flag=1 if buffers are bf16, 0 if fp32 ------
__global__ void sniff_dtype(const unsigned int* __restrict__ x, int* __restrict__ flag) {
  int lane = threadIdx.x & 63;
  int cnt = 0;
  for (int r = 0; r < 4; ++r) {
    unsigned int v = x[lane + r * 64];
    int e = (v >> 7) & 0xFF;
    if (e >= 100 && e <= 145) cnt++;
  }
  for (int d = 1; d < 64; d <<= 1) cnt += __shfl_xor(cnt, d, 64);
  if (lane == 0) *flag = (cnt >= 192) ? 1 : 0;
}

// ---------------- canonicalize x to bf16 ----------------
__global__ __launch_bounds__(256) void convert_x(const void* __restrict__ src,
                                                 bf16_t* __restrict__ dst,
                                                 const int* __restrict__ flag, int n4) {
  int f = *flag;
  int i = blockIdx.x * blockDim.x + threadIdx.x;
  if (i >= n4) return;
  if (f) {
    ((uint2*)dst)[i] = ((const uint2*)src)[i];
  } else {
    const float4 v = ((const float4*)src)[i];
    bf16_t o[4] = {__float2bfloat16(v.x), __float2bfloat16(v.y),
                   __float2bfloat16(v.z), __float2bfloat16(v.w)};
    ((uint2*)dst)[i] = *(const uint2*)o;
  }
}

// -------- transpose W (1024x1024) -> WT[n][k]; slot (z+1)&3 so WO lands at 0 --
__global__ __launch_bounds__(256) void transpose_w(const void* __restrict__ w0,
                                                   const void* __restrict__ w1,
                                                   const void* __restrict__ w2,
                                                   const void* __restrict__ w3,
                                                   bf16_t* __restrict__ wt_base,
                                                   const int* __restrict__ flag) {
  int f = *flag;
  const void* src = (blockIdx.z == 0) ? w0 : (blockIdx.z == 1) ? w1
                  : (blockIdx.z == 2) ? w2 : w3;
  bf16_t* dst = wt_base + (size_t)((blockIdx.z + 1) & 3) * DM * DM;
  __shared__ bf16_t tile[64][65];
  int t = threadIdx.x;
  int tx = t & 63, ty = t >> 6;
  int r0 = blockIdx.y * 64, c0 = blockIdx.x * 64;
  for (int i = 0; i < 64; i += 4) {
    size_t idx = (size_t)(r0 + ty + i) * DM + c0 + tx;
    tile[ty + i][tx] = f ? ((const bf16_t*)src)[idx]
                         : __float2bfloat16(((const float*)src)[idx]);
  }
  __syncthreads();
  for (int i = 0; i < 64; i += 4)
    dst[(size_t)(c0 + ty + i) * DM + r0 + tx] = tile[tx][ty + i];
}

// ---------------- fused QKV GEMM, 128x128 tile, BK=64, plain Q/K epilogue ---
__global__ __launch_bounds__(256) void gemm128_qkv(const bf16_t* __restrict__ A,
                                                   const bf16_t* __restrict__ WTqkv,
                                                   bf16_t* __restrict__ Cq,
                                                   bf16_t* __restrict__ Ck,
                                                   bf16_t* __restrict__ VTo) {
  __shared__ __align__(16) bf16_t As[128][72];   // BK=64 + 8 pad
  __shared__ __align__(16) bf16_t Bs[128][72];
  __shared__ __align__(16) bf16_t T[64][80];
  int t = threadIdx.x;
  int w = t >> 6, lane = t & 63, l15 = lane & 15, quad = lane >> 4;
  int wrow = w >> 1, wcol = w & 1;
  int m0 = blockIdx.y * 128, nx = blockIdx.x, n0 = nx * 128;
  int srow = t >> 1, scol = (t & 1) * 32;
  const bf16_t* ag = A + (size_t)(m0 + srow) * DM + scol;
  const bf16_t* bg = WTqkv + (size_t)(n0 + srow) * DM + scol;
  f32x4 acc[4][4] = {};
  for (int kk = 0; kk < DM; kk += 64) {
    short8 a0 = *(const short8*)(ag + kk);
    short8 a1 = *(const short8*)(ag + kk + 8);
    short8 a2 = *(const short8*)(ag + kk + 16);
    short8 a3 = *(const short8*)(ag + kk + 24);
    short8 b0 = *(const short8*)(bg + kk);
    short8 b1 = *(const short8*)(bg + kk + 8);
    short8 b2 = *(const short8*)(bg + kk + 16);
    short8 b3 = *(const short8*)(bg + kk + 24);
    __syncthreads();
    *(short8*)&As[srow][scol] = a0;       *(short8*)&As[srow][scol + 8] = a1;
    *(short8*)&As[srow][scol + 16] = a2;  *(short8*)&As[srow][scol + 24] = a3;
    *(short8*)&Bs[srow][scol] = b0;       *(short8*)&Bs[srow][scol + 8] = b1;
    *(short8*)&Bs[srow][scol + 16] = b2;  *(short8*)&Bs[srow][scol + 24] = b3;
    __syncthreads();
    short8 af[4][2], bfr[4][2];
#pragma unroll
    for (int mt = 0; mt < 4; ++mt) {
      af[mt][0] = *(const short8*)&As[wrow * 64 + mt * 16 + l15][quad * 8];
      af[mt][1] = *(const short8*)&As[wrow * 64 + mt * 16 + l15][32 + quad * 8];
    }
#pragma unroll
    for (int nt = 0; nt < 4; ++nt) {
      bfr[nt][0] = *(const short8*)&Bs[wcol * 64 + nt * 16 + l15][quad * 8];
      bfr[nt][1] = *(const short8*)&Bs[wcol * 64 + nt * 16 + l15][32 + quad * 8];
    }
#pragma unroll
    for (int mt = 0; mt < 4; ++mt)
#pragma unroll
      for (int nt = 0; nt < 4; ++nt) {
        acc[mt][nt] = mfma16x16x32(af[mt][0], bfr[nt][0], acc[mt][nt]);
        acc[mt][nt] = mfma16x16x32(af[mt][1], bfr[nt][1], acc[mt][nt]);
      }
  }

  int sel = nx >> 3;                 // 0=Q, 1=K, 2=V
  int nc = (nx & 7) * 128;
  if (sel < 2) {
    bf16_t* dst = sel ? Ck : Cq;
#pragma unroll
    for (int mt = 0; mt < 4; ++mt)
#pragma unroll
      for (int nt = 0; nt < 4; ++nt)
#pragma unroll
        for (int r = 0; r < 4; ++r) {
          int m = m0 + wrow * 64 + mt * 16 + quad * 4 + r;
          int col = nc + wcol * 64 + nt * 16 + l15;
          dst[(size_t)m * DM + col] = __float2bfloat16(acc[mt][nt][r]);
        }
  } else {
    int b = m0 >> 11;
    int s_base = m0 & (SEQ - 1);
#pragma unroll
    for (int rh = 0; rh < 2; ++rh)
#pragma unroll
      for (int hh = 0; hh < 2; ++hh) {
        __syncthreads();
        if (wrow == rh && wcol == hh) {
#pragma unroll
          for (int mt = 0; mt < 4; ++mt)
#pragma unroll
            for (int nt = 0; nt < 4; ++nt)
#pragma unroll
              for (int r = 0; r < 4; ++r)
                T[nt * 16 + l15][mt * 16 + quad * 4 + r] = __float2bfloat16(acc[mt][nt][r]);
        }
        __syncthreads();
        int h = (nc >> 6) + hh;
        int drow = t >> 2, soff = (t & 3) * 16;
        size_t obase = ((size_t)(b * NH + h) * DK + drow) * SEQ + s_base + rh * 64 + soff;
        *(short8*)&VTo[obase] = *(const short8*)&T[drow][soff];
        *(short8*)&VTo[obase + 8] = *(const short8*)&T[drow][soff + 8];
      }
  }
}

// ------- RoPE + scatter (Q and K in one launch): [4096][1024] -> [B,NH,SEQ,DK]
__global__ __launch_bounds__(256) void rope_scatter(const bf16_t* __restrict__ srcQ,
                                                    bf16_t* __restrict__ dstQ,
                                                    const bf16_t* __restrict__ srcK,
                                                    bf16_t* __restrict__ dstK,
                                                    const int* __restrict__ tokpos) {
  const bf16_t* src = blockIdx.z ? srcK : srcQ;
  bf16_t* dst = blockIdx.z ? dstK : dstQ;
  int t = threadIdx.x;
  int r = t >> 2, coff = (t & 3) * 16;
  int row = blockIdx.x * 64 + r;
  int h = blockIdx.y;
  int b = row >> 11, s = row & (SEQ - 1);
  const bf16_t* sp = src + (size_t)row * DM + h * DK + coff;
  bf16_t in[16], out[16];
  *(short8*)&in[0] = *(const short8*)sp;
  *(short8*)&in[8] = *(const short8*)(sp + 8);
  float pos = (float)tokpos[row];
#pragma unroll
  for (int j = 0; j < 8; ++j) {
    int d = coff + 2 * j;
    int p = d >> 1;
    float invf = __powf(10000.0f, -(float)p * (1.0f / 32.0f));
    float ang = pos * invf;
    float sn, cs;
    sincosf(ang, &sn, &cs);
    float e = __bfloat162float(in[2 * j]), o = __bfloat162float(in[2 * j + 1]);
    out[2 * j] = __float2bfloat16(e * cs - o * sn);
    out[2 * j + 1] = __float2bfloat16(e * sn + o * cs);
  }
  bf16_t* dp = dst + (((size_t)(b * NH + h)) * SEQ + s) * DK + coff;
  *(short8*)dp = *(const short8*)&out[0];
  *(short8*)(dp + 8) = *(const short8*)&out[8];
}

// ---------------- out-proj GEMM, 128x128 tile, BK=64 ----------------
__global__ __launch_bounds__(256) void gemm128_out(const bf16_t* __restrict__ A,
                                                   const bf16_t* __restrict__ BT,
                                                   void* __restrict__ out,
                                                   const int* __restrict__ flag) {
  __shared__ __align__(16) bf16_t As[128][72];
  __shared__ __align__(16) bf16_t Bs[128][72];
  int f = *flag;
  int t = threadIdx.x;
  int w = t >> 6, lane = t & 63, l15 = lane & 15, quad = lane >> 4;
  int wrow = w >> 1, wcol = w & 1;
  int m0 = blockIdx.y * 128, n0 = blockIdx.x * 128;
  int srow = t >> 1, scol = (t & 1) * 32;
  const bf16_t* ag = A + (size_t)(m0 + srow) * DM + scol;
  const bf16_t* bg = BT + (size_t)(n0 + srow) * DM + scol;
  f32x4 acc[4][4] = {};
  for (int kk = 0; kk < DM; kk += 64) {
    short8 a0 = *(const short8*)(ag + kk);
    short8 a1 = *(const short8*)(ag + kk + 8);
    short8 a2 = *(const short8*)(ag + kk + 16);
    short8 a3 = *(const short8*)(ag + kk + 24);
    short8 b0 = *(const short8*)(bg + kk);
    short8 b1 = *(const short8*)(bg + kk + 8);
    short8 b2 = *(const short8*)(bg + kk + 16);
    short8 b3 = *(const short8*)(bg + kk + 24);
    __syncthreads();
    *(short8*)&As[srow][scol] = a0;       *(short8*)&As[srow][scol + 8] = a1;
    *(short8*)&As[srow][scol + 16] = a2;  *(short8*)&As[srow][scol + 24] = a3;
    *(short8*)&Bs[srow][scol] = b0;       *(short8*)&Bs[srow][scol + 8] = b1;
    *(short8*)&Bs[srow][scol + 16] = b2;  *(short8*)&Bs[srow][scol + 24] = b3;
    __syncthreads();
    short8 af[4][2], bfr[4][2];
#pragma unroll
    for (int mt = 0; mt < 4; ++mt) {
      af[mt][0] = *(const short8*)&As[wrow * 64 + mt * 16 + l15][quad * 8];
      af[mt][1] = *(const short8*)&As[wrow * 64 + mt * 16 + l15][32 + quad * 8];
    }
#pragma unroll
    for (int nt = 0; nt < 4; ++nt) {
      bfr[nt][0] = *(const short8*)&Bs[wcol * 64 + nt * 16 + l15][quad * 8];
      bfr[nt][1] = *(const short8*)&Bs[wcol * 64 + nt * 16 + l15][32 + quad * 8];
    }
#pragma unroll
    for (int mt = 0; mt < 4; ++mt)
#pragma unroll
      for (int nt = 0; nt < 4; ++nt) {
        acc[mt][nt] = mfma16x16x32(af[mt][0], bfr[nt][0], acc[mt][nt]);
        acc[mt][nt] = mfma16x16x32(af[mt][1], bfr[nt][1], acc[mt][nt]);
      }
  }
#pragma unroll
  for (int mt = 0; mt < 4; ++mt)
#pragma unroll
    for (int nt = 0; nt < 4; ++nt)
#pragma unroll
      for (int r = 0; r < 4; ++r) {
        int m = m0 + wrow * 64 + mt * 16 + quad * 4 + r;
        int col = n0 + wcol * 64 + nt * 16 + l15;
        size_t oidx = (size_t)m * DM + col;
        if (f) ((bf16_t*)out)[oidx] = __float2bfloat16(acc[mt][nt][r]);
        else   ((float*)out)[oidx] = acc[mt][nt][r];
      }
}

// -- causal flash attention: SINGLE-Q per block, 4 waves / 256 threads.
// Grid 32x32 = 1024 blocks = 4 blocks/CU = 16 waves/CU (4/SIMD) — the
// latency-hiding occupancy the dual-Q 512-block version lacked, without
// the VGPR squeeze that made the 8-wave version spill (R1: WRITE_SIZE
// 8MB->176MB scratch). blockIdx.x is swizzled so long (p near 31) and
// short (p near 0) q-tiles alternate; co-resident blocks then average
// ~16.5 kv iterations and CUs stay balanced.
__global__ __launch_bounds__(256, 4) void attn_fwd(const bf16_t* __restrict__ Q,
                                                   const bf16_t* __restrict__ K,
                                                   const bf16_t* __restrict__ VT,
                                                   bf16_t* __restrict__ O) {
  int x = blockIdx.x, bh = blockIdx.y;
  int p = (x & 1) ? (31 - (x >> 1)) : (x >> 1);   // interleave long/short
  int b = bh >> 4, h = bh & 15;
  int t = threadIdx.x;
  int w = t >> 6, lane = t & 63, l15 = lane & 15, quad = lane >> 4;
  const size_t base = (size_t)bh * SEQ * DK;
  const bf16_t* Qp = Q + base;
  const bf16_t* Kp = K + base;
  const bf16_t* VTp = VT + base;  // [DK][SEQ]

  __shared__ __align__(16) bf16_t Pb[4][16][72];  // per-wave P staging

  int row = p * 64 + w * 16 + l15;
  short8 qf0 = *(const short8*)(Qp + (size_t)row * DK + quad * 8);
  short8 qf1 = *(const short8*)(Qp + (size_t)row * DK + 32 + quad * 8);

  f32x4 o[4] = {};
  float r[4] = {0.f, 0.f, 0.f, 0.f};

  for (int kb = 0; kb <= p; ++kb) {
    short8 kf0[4], kf1[4], vf0[4], vf1[4];
#pragma unroll
    for (int kt = 0; kt < 4; ++kt) {
      const bf16_t* kr = Kp + (size_t)(kb * 64 + kt * 16 + l15) * DK;
      kf0[kt] = *(const short8*)(kr + quad * 8);
      kf1[kt] = *(const short8*)(kr + 32 + quad * 8);
    }
#pragma unroll
    for (int dt = 0; dt < 4; ++dt) {
      const bf16_t* vr = VTp + (size_t)(dt * 16 + l15) * SEQ + kb * 64;
      vf0[dt] = *(const short8*)(vr + quad * 8);
      vf1[dt] = *(const short8*)(vr + 32 + quad * 8);
    }

    f32x4 sc[4];
#pragma unroll
    for (int kt = 0; kt < 4; ++kt) {
      f32x4 a = {};
      a = mfma16x16x32(qf0, kf0[kt], a);
      a = mfma16x16x32(qf1, kf1[kt], a);
      sc[kt] = a;
    }

    bool diag = (kb == p);
#pragma unroll
    for (int kt = 0; kt < 4; ++kt)
#pragma unroll
      for (int reg = 0; reg < 4; ++reg) {
        float sv = sc[kt][reg] * 0.125f;
        if (diag) {
          int kg = kt * 16 + l15, qg = w * 16 + quad * 4 + reg;
          if (kg > qg) sv = -30000.0f;   // exp underflows to exactly 0
        }
        float pp = __expf(sv);
        r[reg] += pp;
        Pb[w][quad * 4 + reg][kt * 16 + l15] = __float2bfloat16(pp);
      }

    short8 p0 = *(const short8*)&Pb[w][l15][quad * 8];
    short8 p1 = *(const short8*)&Pb[w][l15][32 + quad * 8];
#pragma unroll
    for (int dt = 0; dt < 4; ++dt) {
      o[dt] = mfma16x16x32(p0, vf0[dt], o[dt]);
      o[dt] = mfma16x16x32(p1, vf1[dt], o[dt]);
    }
  }

  // deferred row-sum reduce across the 16-lane groups
  for (int d = 1; d < 16; d <<= 1)
#pragma unroll
    for (int reg = 0; reg < 4; ++reg)
      r[reg] += __shfl_xor(r[reg], d, 64);

#pragma unroll
  for (int dt = 0; dt < 4; ++dt)
#pragma unroll
    for (int reg = 0; reg < 4; ++reg) {
      int col = h * DK + dt * 16 + l15;
      int q = p * 64 + w * 16 + quad * 4 + reg;
      O[((size_t)b * SEQ + q) * DM + col] = __float2bfloat16(o[dt][reg] / r[reg]);
    }
}

extern "C" void kernel_launch(void* const* d_in, const int* in_sizes, int n_in,
                              void* d_out, int out_size, void* d_ws, size_t ws_size,
                              hipStream_t stream) {
  const void* x = d_in[0];
  const int* tokpos = (const int*)d_in[1];
  const void* WQ = d_in[2];
  const void* WK = d_in[3];
  const void* WV = d_in[4];
  const void* WO = d_in[5];

  char* ws = (char*)d_ws;
  const size_t MB = 1024 * 1024;
  bf16_t* WT  = (bf16_t*)ws;              // 0-8 MB: slot0=WO, slots1-3=WQ,WK,WV
  bf16_t* Xc  = (bf16_t*)(ws + 8 * MB);   // 8-16  (dead after gemm128_qkv)
  bf16_t* Cq  = (bf16_t*)(ws + 16 * MB);  // 16-24 (dead after rope)
  bf16_t* Ck  = (bf16_t*)(ws + 24 * MB);  // 24-32 (dead after rope)
  bf16_t* VTb = (bf16_t*)(ws + 32 * MB);  // 32-40
  bf16_t* Qb  = (bf16_t*)(ws + 2 * MB);   // 2-10: overlays dead WTqkv+Xc head
  bf16_t* Kb  = (bf16_t*)(ws + 16 * MB);  // 16-24: overlays dead Cq
  bf16_t* Ab  = (bf16_t*)(ws + 24 * MB);  // 24-32: overlays dead Ck
  int* flag   = (int*)(ws + 40 * MB);

  dim3 blk(256);
  sniff_dtype<<<1, 64, 0, stream>>>((const unsigned int*)x, flag);
  convert_x<<<4096, blk, 0, stream>>>(x, Xc, flag, (SEQ * 2 * DM) / 4);
  transpose_w<<<dim3(16, 16, 4), blk, 0, stream>>>(WQ, WK, WV, WO, WT, flag);
  gemm128_qkv<<<dim3(24, 32), blk, 0, stream>>>(Xc, WT + (size_t)DM * DM, Cq, Ck, VTb);
  rope_scatter<<<dim3(64, 16, 2), blk, 0, stream>>>(Cq, Qb, Ck, Kb, tokpos);
  attn_fwd<<<dim3(32, 32), blk, 0, stream>>>(Qb, Kb, VTb, Ab);
  gemm128_out<<<dim3(8, 32), blk, 0, stream>>>(Ab, WT, d_out, flag);
}

// Round 3
// 303.567 us; speedup vs baseline: 1.3555x; 1.3555x over previous
//
#include <hip/hip_runtime.h>
#include <hip/hip_bf16.h>

typedef __attribute__((ext_vector_type(8))) short short8;
typedef __attribute__((ext_vector_type(4))) float f32x4;
typedef __hip_bfloat16 bf16_t;

#define SEQ 2048
#define DM 1024
#define NH 16
#define DK 64

static __device__ __forceinline__ f32x4 mfma16x16x32(short8 a, short8 b, f32x4 c) {
  return __builtin_amdgcn_mfma_f32_16x16x32_bf16(a, b, c, 0, 0, 0);
}

// ---------------- dtype sniffer: flag=1 if buffers are bf16, 0 if fp32 ------
__global__ void sniff_dtype(const unsigned int* __restrict__ x, int* __restrict__ flag) {
  int lane = threadIdx.x & 63;
  int cnt = 0;
  for (int r = 0; r < 4; ++r) {
    unsigned int v = x[lane + r * 64];
    int e = (v >> 7) & 0xFF;
    if (e >= 100 && e <= 145) cnt++;
  }
  for (int d = 1; d < 64; d <<= 1) cnt += __shfl_xor(cnt, d, 64);
  if (lane == 0) *flag = (cnt >= 192) ? 1 : 0;
}

// ---------------- canonicalize x to bf16 ----------------
__global__ __launch_bounds__(256) void convert_x(const void* __restrict__ src,
                                                 bf16_t* __restrict__ dst,
                                                 const int* __restrict__ flag, int n4) {
  int f = *flag;
  int i = blockIdx.x * blockDim.x + threadIdx.x;
  if (i >= n4) return;
  if (f) {
    ((uint2*)dst)[i] = ((const uint2*)src)[i];
  } else {
    const float4 v = ((const float4*)src)[i];
    bf16_t o[4] = {__float2bfloat16(v.x), __float2bfloat16(v.y),
                   __float2bfloat16(v.z), __float2bfloat16(v.w)};
    ((uint2*)dst)[i] = *(const uint2*)o;
  }
}

// -------- transpose W (1024x1024) -> WT[n][k]; slot (z+1)&3 so WO lands at 0 --
__global__ __launch_bounds__(256) void transpose_w(const void* __restrict__ w0,
                                                   const void* __restrict__ w1,
                                                   const void* __restrict__ w2,
                                                   const void* __restrict__ w3,
                                                   bf16_t* __restrict__ wt_base,
                                                   const int* __restrict__ flag) {
  int f = *flag;
  const void* src = (blockIdx.z == 0) ? w0 : (blockIdx.z == 1) ? w1
                  : (blockIdx.z == 2) ? w2 : w3;
  bf16_t* dst = wt_base + (size_t)((blockIdx.z + 1) & 3) * DM * DM;
  __shared__ bf16_t tile[64][65];
  int t = threadIdx.x;
  int tx = t & 63, ty = t >> 6;
  int r0 = blockIdx.y * 64, c0 = blockIdx.x * 64;
  for (int i = 0; i < 64; i += 4) {
    size_t idx = (size_t)(r0 + ty + i) * DM + c0 + tx;
    tile[ty + i][tx] = f ? ((const bf16_t*)src)[idx]
                         : __float2bfloat16(((const float*)src)[idx]);
  }
  __syncthreads();
  for (int i = 0; i < 64; i += 4)
    dst[(size_t)(c0 + ty + i) * DM + r0 + tx] = tile[tx][ty + i];
}

// ---------------- fused QKV GEMM, 128x128 tile, BK=64, plain Q/K epilogue ---
__global__ __launch_bounds__(256) void gemm128_qkv(const bf16_t* __restrict__ A,
                                                   const bf16_t* __restrict__ WTqkv,
                                                   bf16_t* __restrict__ Cq,
                                                   bf16_t* __restrict__ Ck,
                                                   bf16_t* __restrict__ VTo) {
  __shared__ __align__(16) bf16_t As[128][72];   // BK=64 + 8 pad
  __shared__ __align__(16) bf16_t Bs[128][72];
  __shared__ __align__(16) bf16_t T[64][80];
  int t = threadIdx.x;
  int w = t >> 6, lane = t & 63, l15 = lane & 15, quad = lane >> 4;
  int wrow = w >> 1, wcol = w & 1;
  int m0 = blockIdx.y * 128, nx = blockIdx.x, n0 = nx * 128;
  int srow = t >> 1, scol = (t & 1) * 32;
  const bf16_t* ag = A + (size_t)(m0 + srow) * DM + scol;
  const bf16_t* bg = WTqkv + (size_t)(n0 + srow) * DM + scol;
  f32x4 acc[4][4] = {};
  for (int kk = 0; kk < DM; kk += 64) {
    short8 a0 = *(const short8*)(ag + kk);
    short8 a1 = *(const short8*)(ag + kk + 8);
    short8 a2 = *(const short8*)(ag + kk + 16);
    short8 a3 = *(const short8*)(ag + kk + 24);
    short8 b0 = *(const short8*)(bg + kk);
    short8 b1 = *(const short8*)(bg + kk + 8);
    short8 b2 = *(const short8*)(bg + kk + 16);
    short8 b3 = *(const short8*)(bg + kk + 24);
    __syncthreads();
    *(short8*)&As[srow][scol] = a0;       *(short8*)&As[srow][scol + 8] = a1;
    *(short8*)&As[srow][scol + 16] = a2;  *(short8*)&As[srow][scol + 24] = a3;
    *(short8*)&Bs[srow][scol] = b0;       *(short8*)&Bs[srow][scol + 8] = b1;
    *(short8*)&Bs[srow][scol + 16] = b2;  *(short8*)&Bs[srow][scol + 24] = b3;
    __syncthreads();
    short8 af[4][2], bfr[4][2];
#pragma unroll
    for (int mt = 0; mt < 4; ++mt) {
      af[mt][0] = *(const short8*)&As[wrow * 64 + mt * 16 + l15][quad * 8];
      af[mt][1] = *(const short8*)&As[wrow * 64 + mt * 16 + l15][32 + quad * 8];
    }
#pragma unroll
    for (int nt = 0; nt < 4; ++nt) {
      bfr[nt][0] = *(const short8*)&Bs[wcol * 64 + nt * 16 + l15][quad * 8];
      bfr[nt][1] = *(const short8*)&Bs[wcol * 64 + nt * 16 + l15][32 + quad * 8];
    }
#pragma unroll
    for (int mt = 0; mt < 4; ++mt)
#pragma unroll
      for (int nt = 0; nt < 4; ++nt) {
        acc[mt][nt] = mfma16x16x32(af[mt][0], bfr[nt][0], acc[mt][nt]);
        acc[mt][nt] = mfma16x16x32(af[mt][1], bfr[nt][1], acc[mt][nt]);
      }
  }

  int sel = nx >> 3;                 // 0=Q, 1=K, 2=V
  int nc = (nx & 7) * 128;
  if (sel < 2) {
    bf16_t* dst = sel ? Ck : Cq;
#pragma unroll
    for (int mt = 0; mt < 4; ++mt)
#pragma unroll
      for (int nt = 0; nt < 4; ++nt)
#pragma unroll
        for (int r = 0; r < 4; ++r) {
          int m = m0 + wrow * 64 + mt * 16 + quad * 4 + r;
          int col = nc + wcol * 64 + nt * 16 + l15;
          dst[(size_t)m * DM + col] = __float2bfloat16(acc[mt][nt][r]);
        }
  } else {
    int b = m0 >> 11;
    int s_base = m0 & (SEQ - 1);
#pragma unroll
    for (int rh = 0; rh < 2; ++rh)
#pragma unroll
      for (int hh = 0; hh < 2; ++hh) {
        __syncthreads();
        if (wrow == rh && wcol == hh) {
#pragma unroll
          for (int mt = 0; mt < 4; ++mt)
#pragma unroll
            for (int nt = 0; nt < 4; ++nt)
#pragma unroll
              for (int r = 0; r < 4; ++r)
                T[nt * 16 + l15][mt * 16 + quad * 4 + r] = __float2bfloat16(acc[mt][nt][r]);
        }
        __syncthreads();
        int h = (nc >> 6) + hh;
        int drow = t >> 2, soff = (t & 3) * 16;
        size_t obase = ((size_t)(b * NH + h) * DK + drow) * SEQ + s_base + rh * 64 + soff;
        *(short8*)&VTo[obase] = *(const short8*)&T[drow][soff];
        *(short8*)&VTo[obase + 8] = *(const short8*)&T[drow][soff + 8];
      }
  }
}

// ------- RoPE + scatter (Q and K in one launch): [4096][1024] -> [B,NH,SEQ,DK]
__global__ __launch_bounds__(256) void rope_scatter(const bf16_t* __restrict__ srcQ,
                                                    bf16_t* __restrict__ dstQ,
                                                    const bf16_t* __restrict__ srcK,
                                                    bf16_t* __restrict__ dstK,
                                                    const int* __restrict__ tokpos) {
  const bf16_t* src = blockIdx.z ? srcK : srcQ;
  bf16_t* dst = blockIdx.z ? dstK : dstQ;
  int t = threadIdx.x;
  int r = t >> 2, coff = (t & 3) * 16;
  int row = blockIdx.x * 64 + r;
  int h = blockIdx.y;
  int b = row >> 11, s = row & (SEQ - 1);
  const bf16_t* sp = src + (size_t)row * DM + h * DK + coff;
  bf16_t in[16], out[16];
  *(short8*)&in[0] = *(const short8*)sp;
  *(short8*)&in[8] = *(const short8*)(sp + 8);
  float pos = (float)tokpos[row];
#pragma unroll
  for (int j = 0; j < 8; ++j) {
    int d = coff + 2 * j;
    int p = d >> 1;
    float invf = __powf(10000.0f, -(float)p * (1.0f / 32.0f));
    float ang = pos * invf;
    float sn, cs;
    sincosf(ang, &sn, &cs);
    float e = __bfloat162float(in[2 * j]), o = __bfloat162float(in[2 * j + 1]);
    out[2 * j] = __float2bfloat16(e * cs - o * sn);
    out[2 * j + 1] = __float2bfloat16(e * sn + o * cs);
  }
  bf16_t* dp = dst + (((size_t)(b * NH + h)) * SEQ + s) * DK + coff;
  *(short8*)dp = *(const short8*)&out[0];
  *(short8*)(dp + 8) = *(const short8*)&out[8];
}

// ---------------- out-proj GEMM, 128x128 tile, BK=64 ----------------
__global__ __launch_bounds__(256) void gemm128_out(const bf16_t* __restrict__ A,
                                                   const bf16_t* __restrict__ BT,
                                                   void* __restrict__ out,
                                                   const int* __restrict__ flag) {
  __shared__ __align__(16) bf16_t As[128][72];
  __shared__ __align__(16) bf16_t Bs[128][72];
  int f = *flag;
  int t = threadIdx.x;
  int w = t >> 6, lane = t & 63, l15 = lane & 15, quad = lane >> 4;
  int wrow = w >> 1, wcol = w & 1;
  int m0 = blockIdx.y * 128, n0 = blockIdx.x * 128;
  int srow = t >> 1, scol = (t & 1) * 32;
  const bf16_t* ag = A + (size_t)(m0 + srow) * DM + scol;
  const bf16_t* bg = BT + (size_t)(n0 + srow) * DM + scol;
  f32x4 acc[4][4] = {};
  for (int kk = 0; kk < DM; kk += 64) {
    short8 a0 = *(const short8*)(ag + kk);
    short8 a1 = *(const short8*)(ag + kk + 8);
    short8 a2 = *(const short8*)(ag + kk + 16);
    short8 a3 = *(const short8*)(ag + kk + 24);
    short8 b0 = *(const short8*)(bg + kk);
    short8 b1 = *(const short8*)(bg + kk + 8);
    short8 b2 = *(const short8*)(bg + kk + 16);
    short8 b3 = *(const short8*)(bg + kk + 24);
    __syncthreads();
    *(short8*)&As[srow][scol] = a0;       *(short8*)&As[srow][scol + 8] = a1;
    *(short8*)&As[srow][scol + 16] = a2;  *(short8*)&As[srow][scol + 24] = a3;
    *(short8*)&Bs[srow][scol] = b0;       *(short8*)&Bs[srow][scol + 8] = b1;
    *(short8*)&Bs[srow][scol + 16] = b2;  *(short8*)&Bs[srow][scol + 24] = b3;
    __syncthreads();
    short8 af[4][2], bfr[4][2];
#pragma unroll
    for (int mt = 0; mt < 4; ++mt) {
      af[mt][0] = *(const short8*)&As[wrow * 64 + mt * 16 + l15][quad * 8];
      af[mt][1] = *(const short8*)&As[wrow * 64 + mt * 16 + l15][32 + quad * 8];
    }
#pragma unroll
    for (int nt = 0; nt < 4; ++nt) {
      bfr[nt][0] = *(const short8*)&Bs[wcol * 64 + nt * 16 + l15][quad * 8];
      bfr[nt][1] = *(const short8*)&Bs[wcol * 64 + nt * 16 + l15][32 + quad * 8];
    }
#pragma unroll
    for (int mt = 0; mt < 4; ++mt)
#pragma unroll
      for (int nt = 0; nt < 4; ++nt) {
        acc[mt][nt] = mfma16x16x32(af[mt][0], bfr[nt][0], acc[mt][nt]);
        acc[mt][nt] = mfma16x16x32(af[mt][1], bfr[nt][1], acc[mt][nt]);
      }
  }
#pragma unroll
  for (int mt = 0; mt < 4; ++mt)
#pragma unroll
    for (int nt = 0; nt < 4; ++nt)
#pragma unroll
      for (int r = 0; r < 4; ++r) {
        int m = m0 + wrow * 64 + mt * 16 + quad * 4 + r;
        int col = n0 + wcol * 64 + nt * 16 + l15;
        size_t oidx = (size_t)m * DM + col;
        if (f) ((bf16_t*)out)[oidx] = __float2bfloat16(acc[mt][nt][r]);
        else   ((float*)out)[oidx] = acc[mt][nt][r];
      }
}

// -- causal flash attention: SINGLE-Q per block, 4 waves / 256 threads.
// Grid 32x32 = 1024 blocks = 4 blocks/CU = 16 waves/CU (4/SIMD).
// NO second launch-bounds arg: (256,4) made the compiler cap/split the
// unified VGPR file and spill K/V frags to scratch (R1/R2: VGPR 64/44,
// 31ms first dispatch = lazy scratch alloc). Plain (256) reproduces the
// proven 104-VGPR no-spill codegen, which already allows 4 waves/SIMD.
// Work balance: a CU receives blocks whose linear ids differ by 256,
// i.e. same x, y differing by 8 -> raw=(x+y)&31 differs by 8. Permutation
// f over octants {r, 23-r, r, 55-r} makes every CU's four trip counts
// sum to exactly 66 iterations regardless of r.
__global__ __launch_bounds__(256) void attn_fwd(const bf16_t* __restrict__ Q,
                                                const bf16_t* __restrict__ K,
                                                const bf16_t* __restrict__ VT,
                                                bf16_t* __restrict__ O) {
  int x = blockIdx.x, bh = blockIdx.y;
  int b = bh >> 4, h = bh & 15;
  int raw = (x + bh) & 31;
  int oct = raw >> 3, off = raw & 7;
  int p = (oct == 0) ? off : (oct == 1) ? (15 - off) : (oct == 2) ? (16 + off) : (31 - off);
  int t = threadIdx.x;
  int w = t >> 6, lane = t & 63, l15 = lane & 15, quad = lane >> 4;
  const size_t base = (size_t)bh * SEQ * DK;
  const bf16_t* Qp = Q + base;
  const bf16_t* Kp = K + base;
  const bf16_t* VTp = VT + base;  // [DK][SEQ]

  __shared__ __align__(16) bf16_t Pb[4][16][72];  // per-wave P staging

  int row = p * 64 + w * 16 + l15;
  short8 qf0 = *(const short8*)(Qp + (size_t)row * DK + quad * 8);
  short8 qf1 = *(const short8*)(Qp + (size_t)row * DK + 32 + quad * 8);

  f32x4 o[4] = {};
  float r[4] = {0.f, 0.f, 0.f, 0.f};

  for (int kb = 0; kb <= p; ++kb) {
    short8 kf0[4], kf1[4], vf0[4], vf1[4];
#pragma unroll
    for (int kt = 0; kt < 4; ++kt) {
      const bf16_t* kr = Kp + (size_t)(kb * 64 + kt * 16 + l15) * DK;
      kf0[kt] = *(const short8*)(kr + quad * 8);
      kf1[kt] = *(const short8*)(kr + 32 + quad * 8);
    }
#pragma unroll
    for (int dt = 0; dt < 4; ++dt) {
      const bf16_t* vr = VTp + (size_t)(dt * 16 + l15) * SEQ + kb * 64;
      vf0[dt] = *(const short8*)(vr + quad * 8);
      vf1[dt] = *(const short8*)(vr + 32 + quad * 8);
    }

    f32x4 sc[4];
#pragma unroll
    for (int kt = 0; kt < 4; ++kt) {
      f32x4 a = {};
      a = mfma16x16x32(qf0, kf0[kt], a);
      a = mfma16x16x32(qf1, kf1[kt], a);
      sc[kt] = a;
    }

    bool diag = (kb == p);
#pragma unroll
    for (int kt = 0; kt < 4; ++kt)
#pragma unroll
      for (int reg = 0; reg < 4; ++reg) {
        float sv = sc[kt][reg] * 0.125f;
        if (diag) {
          int kg = kt * 16 + l15, qg = w * 16 + quad * 4 + reg;
          if (kg > qg) sv = -30000.0f;   // exp underflows to exactly 0
        }
        float pp = __expf(sv);
        r[reg] += pp;
        Pb[w][quad * 4 + reg][kt * 16 + l15] = __float2bfloat16(pp);
      }

    short8 p0 = *(const short8*)&Pb[w][l15][quad * 8];
    short8 p1 = *(const short8*)&Pb[w][l15][32 + quad * 8];
#pragma unroll
    for (int dt = 0; dt < 4; ++dt) {
      o[dt] = mfma16x16x32(p0, vf0[dt], o[dt]);
      o[dt] = mfma16x16x32(p1, vf1[dt], o[dt]);
    }
  }

  // deferred row-sum reduce across the 16-lane groups
  for (int d = 1; d < 16; d <<= 1)
#pragma unroll
    for (int reg = 0; reg < 4; ++reg)
      r[reg] += __shfl_xor(r[reg], d, 64);

#pragma unroll
  for (int dt = 0; dt < 4; ++dt)
#pragma unroll
    for (int reg = 0; reg < 4; ++reg) {
      int col = h * DK + dt * 16 + l15;
      int q = p * 64 + w * 16 + quad * 4 + reg;
      O[((size_t)b * SEQ + q) * DM + col] = __float2bfloat16(o[dt][reg] / r[reg]);
    }
}

extern "C" void kernel_launch(void* const* d_in, const int* in_sizes, int n_in,
                              void* d_out, int out_size, void* d_ws, size_t ws_size,
                              hipStream_t stream) {
  const void* x = d_in[0];
  const int* tokpos = (const int*)d_in[1];
  const void* WQ = d_in[2];
  const void* WK = d_in[3];
  const void* WV = d_in[4];
  const void* WO = d_in[5];

  char* ws = (char*)d_ws;
  const size_t MB = 1024 * 1024;
  bf16_t* WT  = (bf16_t*)ws;              // 0-8 MB: slot0=WO, slots1-3=WQ,WK,WV
  bf16_t* Xc  = (bf16_t*)(ws + 8 * MB);   // 8-16  (dead after gemm128_qkv)
  bf16_t* Cq  = (bf16_t*)(ws + 16 * MB);  // 16-24 (dead after rope)
  bf16_t* Ck  = (bf16_t*)(ws + 24 * MB);  // 24-32 (dead after rope)
  bf16_t* VTb = (bf16_t*)(ws + 32 * MB);  // 32-40
  bf16_t* Qb  = (bf16_t*)(ws + 2 * MB);   // 2-10: overlays dead WTqkv+Xc head
  bf16_t* Kb  = (bf16_t*)(ws + 16 * MB);  // 16-24: overlays dead Cq
  bf16_t* Ab  = (bf16_t*)(ws + 24 * MB);  // 24-32: overlays dead Ck
  int* flag   = (int*)(ws + 40 * MB);

  dim3 blk(256);
  sniff_dtype<<<1, 64, 0, stream>>>((const unsigned int*)x, flag);
  convert_x<<<4096, blk, 0, stream>>>(x, Xc, flag, (SEQ * 2 * DM) / 4);
  transpose_w<<<dim3(16, 16, 4), blk, 0, stream>>>(WQ, WK, WV, WO, WT, flag);
  gemm128_qkv<<<dim3(24, 32), blk, 0, stream>>>(Xc, WT + (size_t)DM * DM, Cq, Ck, VTb);
  rope_scatter<<<dim3(64, 16, 2), blk, 0, stream>>>(Cq, Qb, Ck, Kb, tokpos);
  attn_fwd<<<dim3(32, 32), blk, 0, stream>>>(Qb, Kb, VTb, Ab);
  gemm128_out<<<dim3(8, 32), blk, 0, stream>>>(Ab, WT, d_out, flag);
}

// Round 4
// 228.476 us; speedup vs baseline: 1.8009x; 1.3287x over previous
//
#include <hip/hip_runtime.h>
#include <hip/hip_bf16.h>

typedef __attribute__((ext_vector_type(8))) short short8;
typedef __attribute__((ext_vector_type(4))) float f32x4;
typedef __hip_bfloat16 bf16_t;

#define SEQ 2048
#define DM 1024
#define NH 16
#define DK 64

static __device__ __forceinline__ f32x4 mfma16x16x32(short8 a, short8 b, f32x4 c) {
  return __builtin_amdgcn_mfma_f32_16x16x32_bf16(a, b, c, 0, 0, 0);
}

// ---------------- dtype sniffer: flag=1 if buffers are bf16, 0 if fp32 ------
__global__ void sniff_dtype(const unsigned int* __restrict__ x, int* __restrict__ flag) {
  int lane = threadIdx.x & 63;
  int cnt = 0;
  for (int r = 0; r < 4; ++r) {
    unsigned int v = x[lane + r * 64];
    int e = (v >> 7) & 0xFF;
    if (e >= 100 && e <= 145) cnt++;
  }
  for (int d = 1; d < 64; d <<= 1) cnt += __shfl_xor(cnt, d, 64);
  if (lane == 0) *flag = (cnt >= 192) ? 1 : 0;
}

// ---------------- canonicalize x to bf16 ----------------
__global__ __launch_bounds__(256) void convert_x(const void* __restrict__ src,
                                                 bf16_t* __restrict__ dst,
                                                 const int* __restrict__ flag, int n4) {
  int f = *flag;
  int i = blockIdx.x * blockDim.x + threadIdx.x;
  if (i >= n4) return;
  if (f) {
    ((uint2*)dst)[i] = ((const uint2*)src)[i];
  } else {
    const float4 v = ((const float4*)src)[i];
    bf16_t o[4] = {__float2bfloat16(v.x), __float2bfloat16(v.y),
                   __float2bfloat16(v.z), __float2bfloat16(v.w)};
    ((uint2*)dst)[i] = *(const uint2*)o;
  }
}

// -------- transpose W (1024x1024) -> WT[n][k]; slot (z+1)&3 so WO lands at 0 --
__global__ __launch_bounds__(256) void transpose_w(const void* __restrict__ w0,
                                                   const void* __restrict__ w1,
                                                   const void* __restrict__ w2,
                                                   const void* __restrict__ w3,
                                                   bf16_t* __restrict__ wt_base,
                                                   const int* __restrict__ flag) {
  int f = *flag;
  const void* src = (blockIdx.z == 0) ? w0 : (blockIdx.z == 1) ? w1
                  : (blockIdx.z == 2) ? w2 : w3;
  bf16_t* dst = wt_base + (size_t)((blockIdx.z + 1) & 3) * DM * DM;
  __shared__ bf16_t tile[64][65];
  int t = threadIdx.x;
  int tx = t & 63, ty = t >> 6;
  int r0 = blockIdx.y * 64, c0 = blockIdx.x * 64;
  for (int i = 0; i < 64; i += 4) {
    size_t idx = (size_t)(r0 + ty + i) * DM + c0 + tx;
    tile[ty + i][tx] = f ? ((const bf16_t*)src)[idx]
                         : __float2bfloat16(((const float*)src)[idx]);
  }
  __syncthreads();
  for (int i = 0; i < 64; i += 4)
    dst[(size_t)(c0 + ty + i) * DM + r0 + tx] = tile[tx][ty + i];
}

// ---------------- fused QKV GEMM, 128x128 tile, BK=64 ----------------
// V is emitted ROW-MAJOR [b,h,s,d] (same trivial scatter as Q/K) — the
// old [d][SEQ] V^T layout made attn read at 4KB stride (channel camping,
// 62MB HBM fetch on 24MB of input). attn now transposes V in LDS instead.
__global__ __launch_bounds__(256) void gemm128_qkv(const bf16_t* __restrict__ A,
                                                   const bf16_t* __restrict__ WTqkv,
                                                   bf16_t* __restrict__ Cq,
                                                   bf16_t* __restrict__ Ck,
                                                   bf16_t* __restrict__ Vb) {
  __shared__ __align__(16) bf16_t As[128][72];   // BK=64 + 8 pad
  __shared__ __align__(16) bf16_t Bs[128][72];
  int t = threadIdx.x;
  int w = t >> 6, lane = t & 63, l15 = lane & 15, quad = lane >> 4;
  int wrow = w >> 1, wcol = w & 1;
  int m0 = blockIdx.y * 128, nx = blockIdx.x, n0 = nx * 128;
  int srow = t >> 1, scol = (t & 1) * 32;
  const bf16_t* ag = A + (size_t)(m0 + srow) * DM + scol;
  const bf16_t* bg = WTqkv + (size_t)(n0 + srow) * DM + scol;
  f32x4 acc[4][4] = {};
  for (int kk = 0; kk < DM; kk += 64) {
    short8 a0 = *(const short8*)(ag + kk);
    short8 a1 = *(const short8*)(ag + kk + 8);
    short8 a2 = *(const short8*)(ag + kk + 16);
    short8 a3 = *(const short8*)(ag + kk + 24);
    short8 b0 = *(const short8*)(bg + kk);
    short8 b1 = *(const short8*)(bg + kk + 8);
    short8 b2 = *(const short8*)(bg + kk + 16);
    short8 b3 = *(const short8*)(bg + kk + 24);
    __syncthreads();
    *(short8*)&As[srow][scol] = a0;       *(short8*)&As[srow][scol + 8] = a1;
    *(short8*)&As[srow][scol + 16] = a2;  *(short8*)&As[srow][scol + 24] = a3;
    *(short8*)&Bs[srow][scol] = b0;       *(short8*)&Bs[srow][scol + 8] = b1;
    *(short8*)&Bs[srow][scol + 16] = b2;  *(short8*)&Bs[srow][scol + 24] = b3;
    __syncthreads();
    short8 af[4][2], bfr[4][2];
#pragma unroll
    for (int mt = 0; mt < 4; ++mt) {
      af[mt][0] = *(const short8*)&As[wrow * 64 + mt * 16 + l15][quad * 8];
      af[mt][1] = *(const short8*)&As[wrow * 64 + mt * 16 + l15][32 + quad * 8];
    }
#pragma unroll
    for (int nt = 0; nt < 4; ++nt) {
      bfr[nt][0] = *(const short8*)&Bs[wcol * 64 + nt * 16 + l15][quad * 8];
      bfr[nt][1] = *(const short8*)&Bs[wcol * 64 + nt * 16 + l15][32 + quad * 8];
    }
#pragma unroll
    for (int mt = 0; mt < 4; ++mt)
#pragma unroll
      for (int nt = 0; nt < 4; ++nt) {
        acc[mt][nt] = mfma16x16x32(af[mt][0], bfr[nt][0], acc[mt][nt]);
        acc[mt][nt] = mfma16x16x32(af[mt][1], bfr[nt][1], acc[mt][nt]);
      }
  }

  int sel = nx >> 3;                 // 0=Q, 1=K, 2=V
  int nc = (nx & 7) * 128;
  if (sel < 2) {
    bf16_t* dst = sel ? Ck : Cq;
#pragma unroll
    for (int mt = 0; mt < 4; ++mt)
#pragma unroll
      for (int nt = 0; nt < 4; ++nt)
#pragma unroll
        for (int r = 0; r < 4; ++r) {
          int m = m0 + wrow * 64 + mt * 16 + quad * 4 + r;
          int col = nc + wcol * 64 + nt * 16 + l15;
          dst[(size_t)m * DM + col] = __float2bfloat16(acc[mt][nt][r]);
        }
  } else {
#pragma unroll
    for (int mt = 0; mt < 4; ++mt)
#pragma unroll
      for (int nt = 0; nt < 4; ++nt)
#pragma unroll
        for (int r = 0; r < 4; ++r) {
          int m = m0 + wrow * 64 + mt * 16 + quad * 4 + r;   // token 0..4095
          int col = nc + wcol * 64 + nt * 16 + l15;          // dm col
          int b = m >> 11, s = m & (SEQ - 1);
          int h = col >> 6, d = col & 63;
          Vb[(((size_t)(b * NH + h)) * SEQ + s) * DK + d] = __float2bfloat16(acc[mt][nt][r]);
        }
  }
}

// ------- RoPE + scatter (Q and K in one launch): [4096][1024] -> [B,NH,SEQ,DK]
__global__ __launch_bounds__(256) void rope_scatter(const bf16_t* __restrict__ srcQ,
                                                    bf16_t* __restrict__ dstQ,
                                                    const bf16_t* __restrict__ srcK,
                                                    bf16_t* __restrict__ dstK,
                                                    const int* __restrict__ tokpos) {
  const bf16_t* src = blockIdx.z ? srcK : srcQ;
  bf16_t* dst = blockIdx.z ? dstK : dstQ;
  int t = threadIdx.x;
  int r = t >> 2, coff = (t & 3) * 16;
  int row = blockIdx.x * 64 + r;
  int h = blockIdx.y;
  int b = row >> 11, s = row & (SEQ - 1);
  const bf16_t* sp = src + (size_t)row * DM + h * DK + coff;
  bf16_t in[16], out[16];
  *(short8*)&in[0] = *(const short8*)sp;
  *(short8*)&in[8] = *(const short8*)(sp + 8);
  float pos = (float)tokpos[row];
#pragma unroll
  for (int j = 0; j < 8; ++j) {
    int d = coff + 2 * j;
    int p = d >> 1;
    float invf = __powf(10000.0f, -(float)p * (1.0f / 32.0f));
    float ang = pos * invf;
    float sn, cs;
    sincosf(ang, &sn, &cs);
    float e = __bfloat162float(in[2 * j]), o = __bfloat162float(in[2 * j + 1]);
    out[2 * j] = __float2bfloat16(e * cs - o * sn);
    out[2 * j + 1] = __float2bfloat16(e * sn + o * cs);
  }
  bf16_t* dp = dst + (((size_t)(b * NH + h)) * SEQ + s) * DK + coff;
  *(short8*)dp = *(const short8*)&out[0];
  *(short8*)(dp + 8) = *(const short8*)&out[8];
}

// ---------------- out-proj GEMM, 128x128 tile, BK=64 ----------------
__global__ __launch_bounds__(256) void gemm128_out(const bf16_t* __restrict__ A,
                                                   const bf16_t* __restrict__ BT,
                                                   void* __restrict__ out,
                                                   const int* __restrict__ flag) {
  __shared__ __align__(16) bf16_t As[128][72];
  __shared__ __align__(16) bf16_t Bs[128][72];
  int f = *flag;
  int t = threadIdx.x;
  int w = t >> 6, lane = t & 63, l15 = lane & 15, quad = lane >> 4;
  int wrow = w >> 1, wcol = w & 1;
  int m0 = blockIdx.y * 128, n0 = blockIdx.x * 128;
  int srow = t >> 1, scol = (t & 1) * 32;
  const bf16_t* ag = A + (size_t)(m0 + srow) * DM + scol;
  const bf16_t* bg = BT + (size_t)(n0 + srow) * DM + scol;
  f32x4 acc[4][4] = {};
  for (int kk = 0; kk < DM; kk += 64) {
    short8 a0 = *(const short8*)(ag + kk);
    short8 a1 = *(const short8*)(ag + kk + 8);
    short8 a2 = *(const short8*)(ag + kk + 16);
    short8 a3 = *(const short8*)(ag + kk + 24);
    short8 b0 = *(const short8*)(bg + kk);
    short8 b1 = *(const short8*)(bg + kk + 8);
    short8 b2 = *(const short8*)(bg + kk + 16);
    short8 b3 = *(const short8*)(bg + kk + 24);
    __syncthreads();
    *(short8*)&As[srow][scol] = a0;       *(short8*)&As[srow][scol + 8] = a1;
    *(short8*)&As[srow][scol + 16] = a2;  *(short8*)&As[srow][scol + 24] = a3;
    *(short8*)&Bs[srow][scol] = b0;       *(short8*)&Bs[srow][scol + 8] = b1;
    *(short8*)&Bs[srow][scol + 16] = b2;  *(short8*)&Bs[srow][scol + 24] = b3;
    __syncthreads();
    short8 af[4][2], bfr[4][2];
#pragma unroll
    for (int mt = 0; mt < 4; ++mt) {
      af[mt][0] = *(const short8*)&As[wrow * 64 + mt * 16 + l15][quad * 8];
      af[mt][1] = *(const short8*)&As[wrow * 64 + mt * 16 + l15][32 + quad * 8];
    }
#pragma unroll
    for (int nt = 0; nt < 4; ++nt) {
      bfr[nt][0] = *(const short8*)&Bs[wcol * 64 + nt * 16 + l15][quad * 8];
      bfr[nt][1] = *(const short8*)&Bs[wcol * 64 + nt * 16 + l15][32 + quad * 8];
    }
#pragma unroll
    for (int mt = 0; mt < 4; ++mt)
#pragma unroll
      for (int nt = 0; nt < 4; ++nt) {
        acc[mt][nt] = mfma16x16x32(af[mt][0], bfr[nt][0], acc[mt][nt]);
        acc[mt][nt] = mfma16x16x32(af[mt][1], bfr[nt][1], acc[mt][nt]);
      }
  }
#pragma unroll
  for (int mt = 0; mt < 4; ++mt)
#pragma unroll
    for (int nt = 0; nt < 4; ++nt)
#pragma unroll
      for (int r = 0; r < 4; ++r) {
        int m = m0 + wrow * 64 + mt * 16 + quad * 4 + r;
        int col = n0 + wcol * 64 + nt * 16 + l15;
        size_t oidx = (size_t)m * DM + col;
        if (f) ((bf16_t*)out)[oidx] = __float2bfloat16(acc[mt][nt][r]);
        else   ((float*)out)[oidx] = acc[mt][nt][r];
      }
}

// -- causal flash attention: SINGLE-Q per block, 4 waves / 256 threads,
// LDS-staged K/V with register prefetch.
// R3 lesson: 2x occupancy left duration unchanged -> memory path, not
// wave slots, is the limit. Fixes here: (1) K/V tiles staged into LDS
// ONCE per block instead of 4 waves redundantly loading 16KB each from
// global (4x traffic cut); (2) V arrives row-major and is transposed in
// LDS, eliminating the 4KB-stride global V^T reads (channel camping /
// 62MB HBM refetch); (3) next tile prefetched into registers before the
// current tile's MFMA/exp so the global latency hides under compute.
// Work balance across CUs unchanged from R3 (octant permutation, 66
// iters per CU). No second launch-bounds arg (R1/R2 spill lesson).
__global__ __launch_bounds__(256) void attn_fwd(const bf16_t* __restrict__ Q,
                                                const bf16_t* __restrict__ K,
                                                const bf16_t* __restrict__ V,
                                                bf16_t* __restrict__ O) {
  int x = blockIdx.x, bh = blockIdx.y;
  int b = bh >> 4, h = bh & 15;
  int raw = (x + bh) & 31;
  int oct = raw >> 3, off = raw & 7;
  int p = (oct == 0) ? off : (oct == 1) ? (15 - off) : (oct == 2) ? (16 + off) : (31 - off);
  int t = threadIdx.x;
  int w = t >> 6, lane = t & 63, l15 = lane & 15, quad = lane >> 4;
  const size_t base = (size_t)bh * SEQ * DK;
  const bf16_t* Qp = Q + base;
  const bf16_t* Kp = K + base;
  const bf16_t* Vp = V + base;   // row-major [SEQ][DK]

  __shared__ __align__(16) bf16_t Ks[64][72];      // K tile, row-major
  __shared__ __align__(16) bf16_t Vt[64][72];      // V tile, transposed [d][k]
  __shared__ __align__(16) bf16_t Pb[4][16][72];   // per-wave P staging

  int row = p * 64 + w * 16 + l15;
  short8 qf0 = *(const short8*)(Qp + (size_t)row * DK + quad * 8);
  short8 qf1 = *(const short8*)(Qp + (size_t)row * DK + 32 + quad * 8);

  int srow = t >> 2, scoff = (t & 3) * 16;         // staging: row, col-offset
  const bf16_t* kst = Kp + (size_t)srow * DK + scoff;
  const bf16_t* vst = Vp + (size_t)srow * DK + scoff;

  // prologue: loads for kb=0
  short8 kA = *(const short8*)(kst);
  short8 kB = *(const short8*)(kst + 8);
  short8 vA = *(const short8*)(vst);
  short8 vB = *(const short8*)(vst + 8);

  f32x4 o[4] = {};
  float r[4] = {0.f, 0.f, 0.f, 0.f};

  for (int kb = 0; kb <= p; ++kb) {
    __syncthreads();                 // prev iter's LDS reads complete
    *(short8*)&Ks[srow][scoff] = kA;
    *(short8*)&Ks[srow][scoff + 8] = kB;
    {
      bf16_t vv[16];
      *(short8*)&vv[0] = vA;
      *(short8*)&vv[8] = vB;
#pragma unroll
      for (int j = 0; j < 16; ++j) Vt[scoff + j][srow] = vv[j];
    }
    __syncthreads();

    // prefetch next tile into regs (hides under MFMA/exp below);
    // kb==p reloads the same tile harmlessly
    int nkb = (kb < p) ? (kb + 1) : p;
    size_t noff = (size_t)nkb * 64 * DK;
    kA = *(const short8*)(kst + noff);
    kB = *(const short8*)(kst + noff + 8);
    vA = *(const short8*)(vst + noff);
    vB = *(const short8*)(vst + noff + 8);

    short8 kf0[4], kf1[4];
#pragma unroll
    for (int kt = 0; kt < 4; ++kt) {
      kf0[kt] = *(const short8*)&Ks[kt * 16 + l15][quad * 8];
      kf1[kt] = *(const short8*)&Ks[kt * 16 + l15][32 + quad * 8];
    }

    f32x4 sc[4];
#pragma unroll
    for (int kt = 0; kt < 4; ++kt) {
      f32x4 a = {};
      a = mfma16x16x32(qf0, kf0[kt], a);
      a = mfma16x16x32(qf1, kf1[kt], a);
      sc[kt] = a;
    }

    bool diag = (kb == p);
#pragma unroll
    for (int kt = 0; kt < 4; ++kt)
#pragma unroll
      for (int reg = 0; reg < 4; ++reg) {
        float sv = sc[kt][reg] * 0.125f;
        if (diag) {
          int kg = kt * 16 + l15, qg = w * 16 + quad * 4 + reg;
          if (kg > qg) sv = -30000.0f;   // exp underflows to exactly 0
        }
        float pp = __expf(sv);
        r[reg] += pp;
        Pb[w][quad * 4 + reg][kt * 16 + l15] = __float2bfloat16(pp);
      }

    short8 p0 = *(const short8*)&Pb[w][l15][quad * 8];
    short8 p1 = *(const short8*)&Pb[w][l15][32 + quad * 8];
#pragma unroll
    for (int dt = 0; dt < 4; ++dt) {
      short8 vf0 = *(const short8*)&Vt[dt * 16 + l15][quad * 8];
      short8 vf1 = *(const short8*)&Vt[dt * 16 + l15][32 + quad * 8];
      o[dt] = mfma16x16x32(p0, vf0, o[dt]);
      o[dt] = mfma16x16x32(p1, vf1, o[dt]);
    }
  }

  // deferred row-sum reduce across the 16-lane groups
  for (int d = 1; d < 16; d <<= 1)
#pragma unroll
    for (int reg = 0; reg < 4; ++reg)
      r[reg] += __shfl_xor(r[reg], d, 64);

#pragma unroll
  for (int dt = 0; dt < 4; ++dt)
#pragma unroll
    for (int reg = 0; reg < 4; ++reg) {
      int col = h * DK + dt * 16 + l15;
      int q = p * 64 + w * 16 + quad * 4 + reg;
      O[((size_t)b * SEQ + q) * DM + col] = __float2bfloat16(o[dt][reg] / r[reg]);
    }
}

extern "C" void kernel_launch(void* const* d_in, const int* in_sizes, int n_in,
                              void* d_out, int out_size, void* d_ws, size_t ws_size,
                              hipStream_t stream) {
  const void* x = d_in[0];
  const int* tokpos = (const int*)d_in[1];
  const void* WQ = d_in[2];
  const void* WK = d_in[3];
  const void* WV = d_in[4];
  const void* WO = d_in[5];

  char* ws = (char*)d_ws;
  const size_t MB = 1024 * 1024;
  bf16_t* WT  = (bf16_t*)ws;              // 0-8 MB: slot0=WO, slots1-3=WQ,WK,WV
  bf16_t* Xc  = (bf16_t*)(ws + 8 * MB);   // 8-16  (dead after gemm128_qkv)
  bf16_t* Cq  = (bf16_t*)(ws + 16 * MB);  // 16-24 (dead after rope)
  bf16_t* Ck  = (bf16_t*)(ws + 24 * MB);  // 24-32 (dead after rope)
  bf16_t* Vb  = (bf16_t*)(ws + 32 * MB);  // 32-40: V row-major [b,h,s,d]
  bf16_t* Qb  = (bf16_t*)(ws + 2 * MB);   // 2-10: overlays dead WTqkv+Xc head
  bf16_t* Kb  = (bf16_t*)(ws + 16 * MB);  // 16-24: overlays dead Cq
  bf16_t* Ab  = (bf16_t*)(ws + 24 * MB);  // 24-32: overlays dead Ck
  int* flag   = (int*)(ws + 40 * MB);

  dim3 blk(256);
  sniff_dtype<<<1, 64, 0, stream>>>((const unsigned int*)x, flag);
  convert_x<<<4096, blk, 0, stream>>>(x, Xc, flag, (SEQ * 2 * DM) / 4);
  transpose_w<<<dim3(16, 16, 4), blk, 0, stream>>>(WQ, WK, WV, WO, WT, flag);
  gemm128_qkv<<<dim3(24, 32), blk, 0, stream>>>(Xc, WT + (size_t)DM * DM, Cq, Ck, Vb);
  rope_scatter<<<dim3(64, 16, 2), blk, 0, stream>>>(Cq, Qb, Ck, Kb, tokpos);
  attn_fwd<<<dim3(32, 32), blk, 0, stream>>>(Qb, Kb, Vb, Ab);
  gemm128_out<<<dim3(8, 32), blk, 0, stream>>>(Ab, WT, d_out, flag);
}